// Round 3
// baseline (257.787 us; speedup 1.0000x reference)
//
#include <hip/hip_runtime.h>

// RoiAlign / crop_and_resize: B=8, H=64, W=64, C=256, N=512, POOL=7
// One 64-lane wave per output pixel; lane l handles channels [4l,4l+4) as
// a 16B vector (coalesced).
//
// R2b: XCD-aware swizzle (b = blockIdx%8) so each XCD's 4MB L2 holds exactly
// one image slice (4MB) of the feature map, serving the ~822MB of corner
// reads at L2 rate; non-temporal output stores so the 205MB write stream
// doesn't evict fm from L2. Uses clang ext_vector_type for the nontemporal
// builtin (HIP float4 class type is rejected).

#define POOL  7
#define B_    8
#define H_    64
#define W_    64
#define C_    256
#define N_    512
#define PIX_PER_IMG (N_ * POOL * POOL)   // 25088

typedef float v4f __attribute__((ext_vector_type(4)));

__global__ __launch_bounds__(256) void roialign_kernel(
    const float* __restrict__ fm,      // [B,H,W,C]
    const float* __restrict__ boxes,   // [B,N,4] = x1,y1,x2,y2 normalized
    float* __restrict__ out)           // [B,N,POOL,POOL,C]
{
    // XCD swizzle: consecutive blockIdx -> different XCDs (round-robin),
    // so image b sticks to XCD b%8 and its 4MB slice stays L2-resident.
    const int b     = blockIdx.x & 7;
    const int local = blockIdx.x >> 3;          // 0..6271
    const int wave  = threadIdx.x >> 6;         // 0..3
    const int lane  = threadIdx.x & 63;
    const int pixin = local * 4 + wave;         // pixel within image, 0..25087
    if (pixin >= PIX_PER_IMG) return;

    const int px  = pixin % POOL;
    int tmp       = pixin / POOL;
    const int py  = tmp % POOL;
    const int n   = tmp / POOL;                 // 0..511

    const float* box = boxes + ((b << 9) + n) * 4;
    const float bx1 = box[0], by1 = box[1], bx2 = box[2], by2 = box[3];

    // Match reference expression order exactly:
    //   ys = y1*(H-1) + i * ((y2-y1)*(H-1)/(POOL-1))
    const float sy = (by2 - by1) * 63.0f / 6.0f;
    const float sx = (bx2 - bx1) * 63.0f / 6.0f;
    const float yv = by1 * 63.0f + (float)py * sy;
    const float xv = bx1 * 63.0f + (float)px * sx;

    const float yf = floorf(yv), xf = floorf(xv);
    const float fy = yv - yf,    fx = xv - xf;
    const int   y0 = (int)yf,    x0 = (int)xf;

    const int yt = min(max(y0,     0), H_ - 1);
    const int yb = min(max(y0 + 1, 0), H_ - 1);
    const int xl = min(max(x0,     0), W_ - 1);
    const int xr = min(max(x0 + 1, 0), W_ - 1);

    const bool valid = (yv >= 0.0f) && (yv <= (float)(H_ - 1)) &&
                       (xv >= 0.0f) && (xv <= (float)(W_ - 1));

    const int cw = C_ / 4;  // 64 16B-vectors per spatial pixel
    const v4f* f4 = (const v4f*)fm;
    const int imgbase = b * (H_ * W_ * cw);

    const v4f tl = f4[imgbase + (yt * W_ + xl) * cw + lane];
    const v4f tr = f4[imgbase + (yt * W_ + xr) * cw + lane];
    const v4f bl = f4[imgbase + (yb * W_ + xl) * cw + lane];
    const v4f br = f4[imgbase + (yb * W_ + xr) * cw + lane];

    const v4f top = tl + (tr - tl) * fx;
    const v4f bot = bl + (br - bl) * fx;
    v4f o = top + (bot - top) * fy;
    if (!valid) o = (v4f)(0.0f);

    // out pixel index in [B,N,POOL,POOL] order
    const int opix = ((b << 9) + n) * (POOL * POOL) + py * POOL + px;
    __builtin_nontemporal_store(o, &((v4f*)out)[opix * cw + lane]);
}

extern "C" void kernel_launch(void* const* d_in, const int* in_sizes, int n_in,
                              void* d_out, int out_size, void* d_ws, size_t ws_size,
                              hipStream_t stream) {
    const float* fm    = (const float*)d_in[0];   // [8,64,64,256] fp32
    const float* boxes = (const float*)d_in[1];   // [8,512,4] fp32
    float* out         = (float*)d_out;           // [8,512,7,7,256] fp32

    // 4 pixel-waves per 256-thread block; 6272 blocks per image x 8 images.
    const int blocks_per_img = (PIX_PER_IMG + 3) / 4;   // 6272
    const int blocks = blocks_per_img * B_;             // 50176

    roialign_kernel<<<blocks, 256, 0, stream>>>(fm, boxes, out);
}

// Round 4
// 245.932 us; speedup vs baseline: 1.0482x; 1.0482x over previous
//
#include <hip/hip_runtime.h>

// RoiAlign / crop_and_resize: B=8, H=64, W=64, C=256, N=512, POOL=7
//
// R4: one 64-lane wave per (box, py) OUTPUT ROW (7 pixels). Lane l handles
// channels [4l,4l+4) as a 16B vector. Per wave: box math once, then 7
// unrolled pixels x 4 corner loads = 28 independent 16B/lane loads in
// flight (deep MLP), 7 coalesced 1KB NT stores. 28672 waves total vs
// 200704 in R3 — amortizes per-wave VMEM-issue/L1-miss-path overhead,
// and x-adjacent corner reads reuse L1 lines within the wave.
// Keep: %8 image->XCD swizzle, nontemporal output stores.

#define POOL  7
#define B_    8
#define H_    64
#define W_    64
#define C_    256
#define N_    512
#define CW    (C_ / 4)                  // 64 16B-vectors per spatial pixel
#define ROWS_PER_IMG (N_ * POOL)        // 3584 rows per image
#define ROWS_PER_BLOCK 4                // 4 waves per 256-thread block

typedef float v4f __attribute__((ext_vector_type(4)));

__global__ __launch_bounds__(256) void roialign_kernel(
    const float* __restrict__ fm,      // [B,H,W,C]
    const float* __restrict__ boxes,   // [B,N,4] = x1,y1,x2,y2 normalized
    float* __restrict__ out)           // [B,N,POOL,POOL,C]
{
    // XCD swizzle: image b sticks to XCD b (round-robin block dispatch).
    const int b    = blockIdx.x & 7;
    const int rblk = blockIdx.x >> 3;           // 0..895
    const int wave = threadIdx.x >> 6;          // 0..3
    const int lane = threadIdx.x & 63;
    const int row  = rblk * ROWS_PER_BLOCK + wave;   // 0..3583 (exact)
    const int n    = row / POOL;                // 0..511
    const int py   = row - n * POOL;            // 0..6

    const float* box = boxes + ((b << 9) + n) * 4;
    const float bx1 = box[0], by1 = box[1], bx2 = box[2], by2 = box[3];

    // Match reference expression order exactly:
    //   ys = y1*(H-1) + i * ((y2-y1)*(H-1)/(POOL-1))
    const float sy  = (by2 - by1) * 63.0f / 6.0f;
    const float sx  = (bx2 - bx1) * 63.0f / 6.0f;
    const float yv  = by1 * 63.0f + (float)py * sy;
    const float x0v = bx1 * 63.0f;

    const float yf = floorf(yv);
    const float fy = yv - yf;
    const int   y0 = (int)yf;
    const int   yt = min(max(y0,     0), H_ - 1);
    const int   yb = min(max(y0 + 1, 0), H_ - 1);
    const bool  vy = (yv >= 0.0f) && (yv <= 63.0f);

    const v4f* f4  = (const v4f*)fm;
    const int rowT = (b * (H_ * W_) + yt * W_) * CW + lane;
    const int rowB = (b * (H_ * W_) + yb * W_) * CW + lane;

    v4f* o4 = (v4f*)out + ((((b << 9) + n) * POOL + py) * POOL) * CW + lane;

    #pragma unroll
    for (int px = 0; px < POOL; ++px) {
        const float xv = x0v + (float)px * sx;
        const float xf = floorf(xv);
        const float fx = xv - xf;
        const int   x0 = (int)xf;
        const int   xl = min(max(x0,     0), W_ - 1);
        const int   xr = min(max(x0 + 1, 0), W_ - 1);
        const bool  valid = vy && (xv >= 0.0f) && (xv <= 63.0f);

        const v4f tl = f4[rowT + xl * CW];
        const v4f tr = f4[rowT + xr * CW];
        const v4f bl = f4[rowB + xl * CW];
        const v4f br = f4[rowB + xr * CW];

        const v4f top = tl + (tr - tl) * fx;
        const v4f bot = bl + (br - bl) * fx;
        v4f o = top + (bot - top) * fy;
        if (!valid) o = (v4f)(0.0f);

        __builtin_nontemporal_store(o, o4 + px * CW);
    }
}

extern "C" void kernel_launch(void* const* d_in, const int* in_sizes, int n_in,
                              void* d_out, int out_size, void* d_ws, size_t ws_size,
                              hipStream_t stream) {
    const float* fm    = (const float*)d_in[0];   // [8,64,64,256] fp32
    const float* boxes = (const float*)d_in[1];   // [8,512,4] fp32
    float* out         = (float*)d_out;           // [8,512,7,7,256] fp32

    // 4 row-waves per block; 896 blocks per image x 8 images = 7168 blocks.
    const int blocks = (ROWS_PER_IMG / ROWS_PER_BLOCK) * B_;

    roialign_kernel<<<blocks, 256, 0, stream>>>(fm, boxes, out);
}